// Round 11
// baseline (48.663 us; speedup 1.0000x reference)
//
#include <hip/hip_runtime.h>

// DifferentiableCBFLayer: batched HOCBF-QP via ADMM (100 iters).
// 2 lanes per element; each lane owns half the constraint rows; per-iter
// cross-lane reduce via DPP quad_perm swap. 2 waves/SIMD. THIS ROUND: true
// phase-stagger of the two co-resident waves via HW_ID.WAVE_ID slot parity
// (mapping-independent), s_sleep(8) ~512cyc, so each wave's serial-solve
// stall window is filled by the other wave's dense row-work.
// d-space ADMM (rho=1): r = s - Sum A_k|d_k| ; x = Minv r ;
//   d' = A_k x - b_k + 0.5 d + 0.5|d| ; d0 = min(0,-b).

constexpr int NITERS = 100;

typedef float v2 __attribute__((ext_vector_type(2)));

static __device__ __forceinline__ v2 pk_fma(v2 a, v2 b, v2 c) {          // a*b + c
    v2 d; asm("v_pk_fma_f32 %0, %1, %2, %3" : "=v"(d) : "v"(a), "v"(b), "v"(c)); return d;
}
static __device__ __forceinline__ v2 pk_fma_nc(v2 a, v2 b, v2 c) {       // a*b - c
    v2 d; asm("v_pk_fma_f32 %0, %1, %2, %3 neg_lo:[0,0,1] neg_hi:[0,0,1]"
              : "=v"(d) : "v"(a), "v"(b), "v"(c)); return d;
}
static __device__ __forceinline__ v2 pk_add(v2 a, v2 b) {                // a + b
    v2 d; asm("v_pk_add_f32 %0, %1, %2" : "=v"(d) : "v"(a), "v"(b)); return d;
}
static __device__ __forceinline__ v2 pk_sub(v2 a, v2 b) {                // a - b
    v2 d; asm("v_pk_add_f32 %0, %1, %2 neg_lo:[0,1] neg_hi:[0,1]"
              : "=v"(d) : "v"(a), "v"(b)); return d;
}
static __device__ __forceinline__ v2 pk_mul(v2 a, v2 b) {                // a * b
    v2 d; asm("v_pk_mul_f32 %0, %1, %2" : "=v"(d) : "v"(a), "v"(b)); return d;
}
static __device__ __forceinline__ v2 v2abs(v2 a) { return __builtin_elementwise_abs(a); }
static __device__ __forceinline__ v2 vfma_(v2 a, v2 b, v2 c) { return __builtin_elementwise_fma(a, b, c); }
static __device__ __forceinline__ v2 vmin_(v2 a, v2 b)       { return __builtin_elementwise_min(a, b); }

// lane 2k <-> 2k+1 swap (quad_perm [1,0,3,2])
static __device__ __forceinline__ float lane_swap(float x) {
    return __int_as_float(__builtin_amdgcn_mov_dpp(__float_as_int(x), 0xB1, 0xF, 0xF, true));
}

__global__ __launch_bounds__(256, 2)
void cbf_admm_kernel(const float* __restrict__ u_nom,   // (B,2)
                     const float* __restrict__ v_cur,   // (B,1)
                     const float* __restrict__ p_obs,   // (B,16,2)
                     const float* __restrict__ p_ag,    // (B,8,2)
                     const float* __restrict__ v_ag,    // (B,8,2)
                     const float* __restrict__ ag_act,  // (B,8)
                     const float* __restrict__ ob_act,  // (B,16)
                     float* __restrict__ out,           // (B,2)
                     int B)
{
    const int t  = blockIdx.x * blockDim.x + threadIdx.x;
    const int e  = t >> 1;        // batch element
    const int hf = t & 1;         // constraint half owned by this lane
    if (e >= B) return;

    const float v   = v_cur[e];
    const float2 un = *reinterpret_cast<const float2*>(u_nom + 2 * (size_t)e);

    const v2 Z    = {0.f, 0.f};
    const v2 HALF = {0.5f, 0.5f};

    // ---------------- this lane's 8 obstacles (4 packed pairs) ----------------
    v2 ga2[4], gw2[4], bo2[4];
    v2 sa0 = Z, sa1 = Z, sa2 = Z;
    {
        const float4* po = reinterpret_cast<const float4*>(p_obs)  + 4 * (size_t)t;
        const float2* oa = reinterpret_cast<const float2*>(ob_act) + 4 * (size_t)t;
        #pragma unroll
        for (int q = 0; q < 4; ++q) {
            const float4 p  = po[q];
            const float2 ac = oa[q];
            const v2 lx = {p.x, p.z};
            const v2 ly = {p.y, p.w};
            const v2 act = {ac.x, ac.y};
            ga2[q] = 2.f * lx;
            gw2[q] = (2.f * v) * ly;
            const v2 h_obs = lx * lx + ly * ly - 0.25f;              // D_OBS^2
            const v2 hdot  = (-2.f * v) * lx;
            const v2 bb = (2.f * v * v + 2.f * hdot + h_obs) * act;  // DAMPING=2, STIFF=1
            bo2[q] = bb;
            sa0 = vfma_(ga2[q], bb, sa0);
            sa1 = vfma_(gw2[q], bb, sa1);
            sa2 = sa2 + bb;                                          // col2 = -1
        }
    }

    // ---------------- this lane's 4 agents (2 packed pairs) ----------------
    v2 gaa2[2], gwa2[2], ba2[2], bc2[2];
    {
        const float4* pa = reinterpret_cast<const float4*>(p_ag)   + 2 * (size_t)t;
        const float4* va = reinterpret_cast<const float4*>(v_ag)   + 2 * (size_t)t;
        const float2* aa = reinterpret_cast<const float2*>(ag_act) + 2 * (size_t)t;
        #pragma unroll
        for (int q = 0; q < 2; ++q) {
            const float4 p  = pa[q];
            const float4 w4 = va[q];
            const float2 ac = aa[q];
            const v2 lx = {p.x,  p.z},  ly = {p.y,  p.w};
            const v2 vx = {w4.x, w4.z}, vy = {w4.y, w4.w};
            const v2 act = {ac.x, ac.y};
            const v2 d2  = lx * lx + ly * ly;
            const v2 hdot = (-2.f * v) * lx + 2.f * (lx * vx + ly * vy);
            const v2 hddc = (2.f * v * v) + (-4.f * v) * vx + 2.f * (vx * vx + vy * vy);
            gaa2[q] = (2.f * lx) * act;
            gwa2[q] = ((2.f * v) * ly - 2.f * ly * vx + 2.f * lx * vy) * act;
            const v2 ba = (hddc + 2.f * hdot + (d2 - 0.25f)) * act;   // avoid
            const v2 bc = (-hddc - 2.f * hdot + (100.f - d2)) * act;  // conn
            ba2[q] = ba;
            bc2[q] = bc;
            const v2 dba = ba - bc;
            sa0 = vfma_(gaa2[q], dba, sa0);
            sa1 = vfma_(gwa2[q], dba, sa1);
        }
    }

    // ---------------- M partials ----------------
    v2 m00 = Z, m01 = Z, m11 = Z, m02 = Z, m12 = Z;
    #pragma unroll
    for (int q = 0; q < 4; ++q) {
        m00 = vfma_(ga2[q], ga2[q], m00);
        m01 = vfma_(ga2[q], gw2[q], m01);
        m11 = vfma_(gw2[q], gw2[q], m11);
        m02 = m02 - ga2[q];
        m12 = m12 - gw2[q];
    }
    #pragma unroll
    for (int q = 0; q < 2; ++q) {     // avoid + conn contribute twice
        const v2 g2 = gaa2[q] + gaa2[q];
        m00 = vfma_(g2, gaa2[q], m00);
        m01 = vfma_(g2, gwa2[q], m01);
        m11 = vfma_(gwa2[q] + gwa2[q], gwa2[q], m11);
    }

    // ---------------- one-time cross-lane reduce of s and M ----------------
    const float s0p = sa0.x + sa0.y, s1p = sa1.x + sa1.y, s2p = sa2.x + sa2.y;
    const float s0 = fmaf(2.f, un.x, s0p + lane_swap(s0p));
    const float s1 = fmaf(2.f, un.y, s1p + lane_swap(s1p));
    const float s2 = -(s2p + lane_swap(s2p));
    const float M00p = m00.x + m00.y, M01p = m01.x + m01.y, M11p = m11.x + m11.y;
    const float M02p = m02.x + m02.y, M12p = m12.x + m12.y;
    const float M00 = M00p + lane_swap(M00p) + 4.f;   // Q(2) + 2 box rows
    const float M01 = M01p + lane_swap(M01p);
    const float M11 = M11p + lane_swap(M11p) + 4.f;
    const float M02 = M02p + lane_swap(M02p);
    const float M12 = M12p + lane_swap(M12p);
    const float M22 = 217.f;          // 2*W_SLACK + 16 obs rows + slack box row
    const float c00 = M11 * M22 - M12 * M12;
    const float c01 = M02 * M12 - M01 * M22;
    const float c02 = M01 * M12 - M02 * M11;
    const float det = M00 * c00 + M01 * c01 + M02 * c02;
    const float id  = 1.f / det;
    const float i00 = c00 * id, i01 = c01 * id, i02 = c02 * id;
    const float i11 = (M00 * M22 - M02 * M02) * id;
    const float i12 = (M01 * M02 - M00 * M12) * id;
    const float i22 = (M00 * M11 - M01 * M01) * id;

    // ---------------- init d = min(0,-b) ----------------
    v2 do2[4], da2[2], dc2[2];
    #pragma unroll
    for (int q = 0; q < 4; ++q) do2[q] = vmin_(Z, -bo2[q]);
    #pragma unroll
    for (int q = 0; q < 2; ++q) { da2[q] = vmin_(Z, -ba2[q]); dc2[q] = vmin_(Z, -bc2[q]); }
    // box + slack rows: duplicated identically on both lanes
    float db0 = -1.f, db1 = -1.f, db2 = -1.f, db3 = -1.f, d4 = 0.f;

    float x0 = 0.f, x1 = 0.f, x2 = 0.f;

    // -------- TRUE phase-stagger: HW_ID.WAVE_ID slot parity (bits [3:0]) --------
    // getreg imm = id | (offset<<6) | ((size-1)<<11) = 4 | 0 | (3<<11) = 6148
    {
        const unsigned wslot = __builtin_amdgcn_s_getreg(6148);
        if (wslot & 1) __builtin_amdgcn_s_sleep(8);   // ~512 cyc ≈ half an iteration
    }

    #pragma unroll 1
    for (int it = 0; it < NITERS; ++it) {
        // ---- partial reduce: Sum A_k |d_k| over this lane's rows ----
        v2 A0 = Z, A1 = Z, AT = Z;
        v2 ado[4], ada[2], adc[2];
        #pragma unroll
        for (int q = 0; q < 4; ++q) {
            const v2 ad = v2abs(do2[q]);
            ado[q] = ad;
            A0 = pk_fma(ga2[q], ad, A0);
            A1 = pk_fma(gw2[q], ad, A1);
            AT = pk_add(AT, ad);
        }
        #pragma unroll
        for (int q = 0; q < 2; ++q) {
            const v2 aa_ = v2abs(da2[q]);  ada[q] = aa_;
            const v2 cc_ = v2abs(dc2[q]);  adc[q] = cc_;
            const v2 diff = pk_sub(aa_, cc_);
            A0 = pk_fma(gaa2[q], diff, A0);
            A1 = pk_fma(gwa2[q], diff, A1);
        }
        // box contributions, 0.5-weighted (each lane adds half; swap sums them)
        const float rb0 = fabsf(db0) - fabsf(db1);
        const float rb1 = fabsf(db2) - fabsf(db3);
        const float R0p = fmaf(-0.5f, rb0, A0.x + A0.y);
        const float R1p = fmaf(-0.5f, rb1, A1.x + A1.y);
        const float R2p = fmaf( 0.5f, fabsf(d4), AT.x + AT.y);

        // ---- cross-lane reduce (bitwise-identical on both lanes) ----
        const float r0 = s0 - (R0p + lane_swap(R0p));
        const float r1 = s1 - (R1p + lane_swap(R1p));
        const float r2 = s2 + (R2p + lane_swap(R2p));

        // ---- x = Minv r (duplicated) ----
        x0 = fmaf(i00, r0, fmaf(i01, r1, i02 * r2));
        x1 = fmaf(i01, r0, fmaf(i11, r1, i12 * r2));
        x2 = fmaf(i02, r0, fmaf(i12, r1, i22 * r2));

        // ---- updates: d' = A_k x - b_k + 0.5 d + 0.5|d| ----
        const v2 X0 = {x0, x0}, X1 = {x1, x1};
        const float nx2 = -x2;
        const v2 MX2 = {nx2, nx2};
        #pragma unroll
        for (int q = 0; q < 4; ++q) {
            v2 u = pk_fma(HALF, do2[q], pk_sub(MX2, bo2[q]));
            u = pk_fma(HALF, ado[q], u);
            u = pk_fma(gw2[q], X1, u);
            do2[q] = pk_fma(ga2[q], X0, u);
        }
        #pragma unroll
        for (int q = 0; q < 2; ++q) {
            const v2 va_ = pk_fma(gaa2[q], X0, pk_mul(gwa2[q], X1));
            v2 u = pk_fma(HALF, da2[q], pk_sub(va_, ba2[q]));
            da2[q] = pk_fma(HALF, ada[q], u);
            v2 w = pk_fma_nc(HALF, dc2[q], pk_add(va_, bc2[q]));
            dc2[q] = pk_fma(HALF, adc[q], w);
        }
        const float e0 = x0 + 1.f, e1 = x0 - 1.f;
        const float e2 = x1 + 1.f, e3 = x1 - 1.f;
        db0 = fmaxf(db0, 0.f) - e0;
        db1 = fmaxf(db1, 0.f) + e1;
        db2 = fmaxf(db2, 0.f) - e2;
        db3 = fmaxf(db3, 0.f) + e3;
        d4  = fmaxf(d4, 0.f) - x2;
    }

    if (hf == 0)
        reinterpret_cast<float2*>(out)[e] = make_float2(x0, x1);
}

extern "C" void kernel_launch(void* const* d_in, const int* in_sizes, int n_in,
                              void* d_out, int out_size, void* d_ws, size_t ws_size,
                              hipStream_t stream) {
    const float* u_nom  = (const float*)d_in[0];
    const float* v_cur  = (const float*)d_in[1];
    const float* p_obs  = (const float*)d_in[2];
    const float* p_ag   = (const float*)d_in[3];
    const float* v_ag   = (const float*)d_in[4];
    const float* ag_act = (const float*)d_in[5];
    const float* ob_act = (const float*)d_in[6];
    float* out = (float*)d_out;

    const int B = in_sizes[1];            // v_current is (B,1)
    const int threads = 2 * B;
    dim3 block(256), grid((threads + 255) / 256);
    hipLaunchKernelGGL(cbf_admm_kernel, grid, block, 0, stream,
                       u_nom, v_cur, p_obs, p_ag, v_ag, ag_act, ob_act, out, B);
}

// Round 12
// 43.135 us; speedup vs baseline: 1.1282x; 1.1282x over previous
//
#include <hip/hip_runtime.h>

// DifferentiableCBFLayer: batched HOCBF-QP via ADMM (100 iters), 1 thread = 1 elem.
// d-space ADMM (rho=1), state d = w - b per constraint row:
//   t   = b - |d|
//   r   = s - Sum A_k|d_k|,  s = -q + A^T b  (precomputed; box consts cancel)
//   x   = Minv r
//   d'  = A_k x - b_k + 0.5 d + 0.5|d|
// Inner loop forced to VOP3P packed fp32 via inline asm (v_pk_fma/add_f32).
// [Session best: R5 @ 43.07 us. Reverted here after R6-R11 attacks (iteration
//  cut, scalar-modifier form, 2-lane splits, wave stagger, fusion, waves_per_eu)
//  all failed to beat it. Wall tracks VALU inst count at ~5.8 cyc/inst.]

constexpr int NITERS = 100;

typedef float v2 __attribute__((ext_vector_type(2)));

// ---- guaranteed-packed fp32 ops (gfx90a-lineage VOP3P) ----
static __device__ __forceinline__ v2 pk_fma(v2 a, v2 b, v2 c) {          // a*b + c
    v2 d; asm("v_pk_fma_f32 %0, %1, %2, %3" : "=v"(d) : "v"(a), "v"(b), "v"(c)); return d;
}
static __device__ __forceinline__ v2 pk_fma_nc(v2 a, v2 b, v2 c) {       // a*b - c
    v2 d; asm("v_pk_fma_f32 %0, %1, %2, %3 neg_lo:[0,0,1] neg_hi:[0,0,1]"
              : "=v"(d) : "v"(a), "v"(b), "v"(c)); return d;
}
static __device__ __forceinline__ v2 pk_add(v2 a, v2 b) {                // a + b
    v2 d; asm("v_pk_add_f32 %0, %1, %2" : "=v"(d) : "v"(a), "v"(b)); return d;
}
static __device__ __forceinline__ v2 pk_sub(v2 a, v2 b) {                // a - b
    v2 d; asm("v_pk_add_f32 %0, %1, %2 neg_lo:[0,1] neg_hi:[0,1]"
              : "=v"(d) : "v"(a), "v"(b)); return d;
}
static __device__ __forceinline__ v2 pk_mul(v2 a, v2 b) {                // a * b
    v2 d; asm("v_pk_mul_f32 %0, %1, %2" : "=v"(d) : "v"(a), "v"(b)); return d;
}
static __device__ __forceinline__ v2 v2abs(v2 a) { return __builtin_elementwise_abs(a); } // 2x v_and
static __device__ __forceinline__ v2 vfma_(v2 a, v2 b, v2 c) { return __builtin_elementwise_fma(a, b, c); }
static __device__ __forceinline__ v2 vmin_(v2 a, v2 b)       { return __builtin_elementwise_min(a, b); }

__global__ __launch_bounds__(256, 1)
void cbf_admm_kernel(const float* __restrict__ u_nom,   // (B,2)
                     const float* __restrict__ v_cur,   // (B,1)
                     const float* __restrict__ p_obs,   // (B,16,2)
                     const float* __restrict__ p_ag,    // (B,8,2)
                     const float* __restrict__ v_ag,    // (B,8,2)
                     const float* __restrict__ ag_act,  // (B,8)
                     const float* __restrict__ ob_act,  // (B,16)
                     float* __restrict__ out,           // (B,2)
                     int B)
{
    const int b = blockIdx.x * blockDim.x + threadIdx.x;
    if (b >= B) return;

    const float v   = v_cur[b];
    const float2 un = *reinterpret_cast<const float2*>(u_nom + 2 * (size_t)b);

    const v2 Z    = {0.f, 0.f};
    const v2 HALF = {0.5f, 0.5f};

    // ---------------- build obstacle rows (2 per v2) ----------------
    v2 ga2[8], gw2[8], bo2[8];
    v2 sa0 = Z, sa1 = Z, sa2 = Z;
    {
        const float4* po = reinterpret_cast<const float4*>(p_obs + (size_t)b * 32);
        const float2* oa = reinterpret_cast<const float2*>(ob_act + (size_t)b * 16);
        #pragma unroll
        for (int q = 0; q < 8; ++q) {
            const float4 p  = po[q];
            const float2 ac = oa[q];
            const v2 lx = {p.x, p.z};
            const v2 ly = {p.y, p.w};
            const v2 act = {ac.x, ac.y};
            ga2[q] = 2.f * lx;
            gw2[q] = (2.f * v) * ly;
            const v2 h_obs = lx * lx + ly * ly - 0.25f;              // D_OBS^2
            const v2 hdot  = (-2.f * v) * lx;
            const v2 bb = (2.f * v * v + 2.f * hdot + h_obs) * act;  // DAMPING=2, STIFF=1
            bo2[q] = bb;
            sa0 = vfma_(ga2[q], bb, sa0);
            sa1 = vfma_(gw2[q], bb, sa1);
            sa2 = sa2 + bb;
        }
    }

    // ---------------- build agent rows (2 per v2) ----------------
    v2 gaa2[4], gwa2[4], ba2[4], bc2[4];
    {
        const float4* pa = reinterpret_cast<const float4*>(p_ag  + (size_t)b * 16);
        const float4* va = reinterpret_cast<const float4*>(v_ag  + (size_t)b * 16);
        const float2* aa = reinterpret_cast<const float2*>(ag_act + (size_t)b * 8);
        #pragma unroll
        for (int q = 0; q < 4; ++q) {
            const float4 p  = pa[q];
            const float4 w4 = va[q];
            const float2 ac = aa[q];
            const v2 lx = {p.x,  p.z},  ly = {p.y,  p.w};
            const v2 vx = {w4.x, w4.z}, vy = {w4.y, w4.w};
            const v2 act = {ac.x, ac.y};
            const v2 d2  = lx * lx + ly * ly;
            const v2 hdot = (-2.f * v) * lx + 2.f * (lx * vx + ly * vy);
            const v2 hddc = (2.f * v * v) + (-4.f * v) * vx + 2.f * (vx * vx + vy * vy);
            gaa2[q] = (2.f * lx) * act;
            gwa2[q] = ((2.f * v) * ly - 2.f * ly * vx + 2.f * lx * vy) * act;
            const v2 ba = (hddc + 2.f * hdot + (d2 - 0.25f)) * act;   // avoid
            const v2 bc = (-hddc - 2.f * hdot + (100.f - d2)) * act;  // conn
            ba2[q] = ba;
            bc2[q] = bc;
            const v2 dba = ba - bc;
            sa0 = vfma_(gaa2[q], dba, sa0);
            sa1 = vfma_(gwa2[q], dba, sa1);
        }
    }
    const float s0 = 2.f * un.x + sa0.x + sa0.y;
    const float s1 = 2.f * un.y + sa1.x + sa1.y;
    const float s2 = -(sa2.x + sa2.y);

    // ---------------- M = Q + A^T A, closed-form inverse ----------------
    v2 m00 = Z, m01 = Z, m11 = Z, m02 = Z, m12 = Z;
    #pragma unroll
    for (int q = 0; q < 8; ++q) {
        m00 = vfma_(ga2[q], ga2[q], m00);
        m01 = vfma_(ga2[q], gw2[q], m01);
        m11 = vfma_(gw2[q], gw2[q], m11);
        m02 = m02 - ga2[q];
        m12 = m12 - gw2[q];
    }
    #pragma unroll
    for (int q = 0; q < 4; ++q) {
        const v2 g2 = gaa2[q] + gaa2[q];
        m00 = vfma_(g2, gaa2[q], m00);
        m01 = vfma_(g2, gwa2[q], m01);
        m11 = vfma_(gwa2[q] + gwa2[q], gwa2[q], m11);
    }
    const float M00 = m00.x + m00.y + 4.f;
    const float M01 = m01.x + m01.y;
    const float M11 = m11.x + m11.y + 4.f;
    const float M02 = m02.x + m02.y;
    const float M12 = m12.x + m12.y;
    const float M22 = 217.f;
    const float c00 = M11 * M22 - M12 * M12;
    const float c01 = M02 * M12 - M01 * M22;
    const float c02 = M01 * M12 - M02 * M11;
    const float det = M00 * c00 + M01 * c01 + M02 * c02;
    const float id  = 1.f / det;
    const float i00 = c00 * id, i01 = c01 * id, i02 = c02 * id;
    const float i11 = (M00 * M22 - M02 * M02) * id;
    const float i12 = (M01 * M02 - M00 * M12) * id;
    const float i22 = (M00 * M11 - M01 * M01) * id;

    // ---------------- init d = min(0, -b) ----------------
    v2 do2[8], da2[4], dc2[4];
    #pragma unroll
    for (int q = 0; q < 8; ++q) do2[q] = vmin_(Z, -bo2[q]);
    #pragma unroll
    for (int q = 0; q < 4; ++q) { da2[q] = vmin_(Z, -ba2[q]); dc2[q] = vmin_(Z, -bc2[q]); }
    float db0 = -1.f, db1 = -1.f, db2 = -1.f, db3 = -1.f, d4 = 0.f;

    float x0 = 0.f, x1 = 0.f, x2 = 0.f;

    #pragma unroll 1
    for (int it = 0; it < NITERS; ++it) {
        // ---- reduce: ACC = Sum A_k |d_k| ----
        v2 A0 = Z, A1 = Z, AT = Z;
        v2 ado[8], ada[4], adc[4];
        #pragma unroll
        for (int q = 0; q < 8; ++q) {
            const v2 ad = v2abs(do2[q]);
            ado[q] = ad;
            A0 = pk_fma(ga2[q], ad, A0);
            A1 = pk_fma(gw2[q], ad, A1);
            AT = pk_add(AT, ad);
        }
        #pragma unroll
        for (int q = 0; q < 4; ++q) {
            const v2 aa = v2abs(da2[q]);  ada[q] = aa;
            const v2 cc = v2abs(dc2[q]);  adc[q] = cc;
            const v2 diff = pk_sub(aa, cc);
            A0 = pk_fma(gaa2[q], diff, A0);
            A1 = pk_fma(gwa2[q], diff, A1);
        }
        const float rb0 = fabsf(db0) - fabsf(db1);
        const float rb1 = fabsf(db2) - fabsf(db3);
        const float r0 = (s0 + rb0) - (A0.x + A0.y);
        const float r1 = (s1 + rb1) - (A1.x + A1.y);
        const float r2 = (s2 + fabsf(d4)) + (AT.x + AT.y);

        // ---- x = Minv r ----
        x0 = fmaf(i00, r0, fmaf(i01, r1, i02 * r2));
        x1 = fmaf(i01, r0, fmaf(i11, r1, i12 * r2));
        x2 = fmaf(i02, r0, fmaf(i12, r1, i22 * r2));

        // ---- updates: d' = A_k x - b_k + 0.5 d + 0.5 |d| ----
        const v2 X0 = {x0, x0}, X1 = {x1, x1};
        const float nx2 = -x2;
        const v2 MX2 = {nx2, nx2};
        #pragma unroll
        for (int q = 0; q < 8; ++q) {
            v2 u = pk_fma(HALF, do2[q], pk_sub(MX2, bo2[q]));
            u = pk_fma(HALF, ado[q], u);
            u = pk_fma(gw2[q], X1, u);
            do2[q] = pk_fma(ga2[q], X0, u);
        }
        #pragma unroll
        for (int q = 0; q < 4; ++q) {
            const v2 va_ = pk_fma(gaa2[q], X0, pk_mul(gwa2[q], X1));
            // avoid: da' = va - ba + 0.5 da + 0.5 |da|
            v2 u = pk_fma(HALF, da2[q], pk_sub(va_, ba2[q]));
            da2[q] = pk_fma(HALF, ada[q], u);
            // conn: dc' = -va - bc + 0.5 dc + 0.5 |dc|
            v2 w = pk_fma_nc(HALF, dc2[q], pk_add(va_, bc2[q]));
            dc2[q] = pk_fma(HALF, adc[q], w);
        }
        const float c0m = -x0 - 1.f, c0p = x0 - 1.f;
        const float c1m = -x1 - 1.f, c1p = x1 - 1.f;
        db0 = fmaxf(db0, 0.f) + c0m;
        db1 = fmaxf(db1, 0.f) + c0p;
        db2 = fmaxf(db2, 0.f) + c1m;
        db3 = fmaxf(db3, 0.f) + c1p;
        d4  = fmaxf(d4, 0.f) - x2;
    }

    reinterpret_cast<float2*>(out)[b] = make_float2(x0, x1);
}

extern "C" void kernel_launch(void* const* d_in, const int* in_sizes, int n_in,
                              void* d_out, int out_size, void* d_ws, size_t ws_size,
                              hipStream_t stream) {
    const float* u_nom  = (const float*)d_in[0];
    const float* v_cur  = (const float*)d_in[1];
    const float* p_obs  = (const float*)d_in[2];
    const float* p_ag   = (const float*)d_in[3];
    const float* v_ag   = (const float*)d_in[4];
    const float* ag_act = (const float*)d_in[5];
    const float* ob_act = (const float*)d_in[6];
    float* out = (float*)d_out;

    const int B = in_sizes[1];            // v_current is (B,1)
    dim3 block(256), grid((B + 255) / 256);
    hipLaunchKernelGGL(cbf_admm_kernel, grid, block, 0, stream,
                       u_nom, v_cur, p_obs, p_ag, v_ag, ag_act, ob_act, out, B);
}